// Round 15
// baseline (452.703 us; speedup 1.0000x reference)
//
#include <hip/hip_runtime.h>
#include <math.h>

#define N_NODES  100000
#define N_EDGES  3200000
#define N_GRAPHS 256

// DIMS = [38, 64, 32, 16]

#define BSHIFT 9
#define NB 196                                   // buckets of 512 nodes
#define CAP 18432                                // bucket window capacity (mean 16384, +16 sigma)
#define NBLK 640
#define EPB ((N_EDGES + NBLK - 1) / NBLK)        // 5000 edges per block

typedef _Float16 f16;
typedef _Float16 f16x2 __attribute__((ext_vector_type(2)));

__device__ __forceinline__ float fast_tanh(float x) {
    x = fminf(20.f, fmaxf(-20.f, x));
    float e = __expf(2.f * x);
    return (e - 1.f) / (e + 1.f);
}

// pack two f32 -> bf16x2 (RNE)
__device__ __forceinline__ unsigned int pack_bf2(float a, float b) {
    unsigned int ua = __float_as_uint(a);
    unsigned int ub = __float_as_uint(b);
    ua += 0x7fffu + ((ua >> 16) & 1u);
    ub += 0x7fffu + ((ub >> 16) & 1u);
    return (ua >> 16) | (ub & 0xffff0000u);
}

__device__ __forceinline__ f16x2 u2h(unsigned int u) { union { unsigned int u; f16x2 h; } c; c.u = u; return c.h; }
__device__ __forceinline__ unsigned int h2u(f16x2 h) { union { unsigned int u; f16x2 h; } c; c.h = h; return c.u; }
__device__ __forceinline__ unsigned int mkh2(float a, float b) {
    f16x2 v; v.x = (f16)a; v.y = (f16)b; return h2u(v);
}

__device__ __forceinline__ float fdot2f(f16x2 a, f16x2 b, float c) {
#if __has_builtin(__builtin_amdgcn_fdot2)
    return __builtin_amdgcn_fdot2(a, b, c, false);
#else
    return c + (float)a.x * (float)b.x + (float)a.y * (float)b.y;
#endif
}

// ---------------- fused bucket scatter: count -> reserve -> write (fixed windows) ----------------
__global__ __launch_bounds__(256) void k_scatter2(const int* __restrict__ src,
                                                  const int* __restrict__ dst,
                                                  int* __restrict__ bucket_cnt,
                                                  int* __restrict__ ebuf) {
    __shared__ int hist[NB];
    __shared__ int base[NB];
    __shared__ int cur[NB];
    int tid = threadIdx.x, b = blockIdx.x;
    for (int i = tid; i < NB; i += 256) { hist[i] = 0; cur[i] = 0; }
    __syncthreads();
    int lo = b * EPB, hi = min(lo + EPB, N_EDGES);
    for (int e = lo + tid; e < hi; e += 256)
        atomicAdd(&hist[((unsigned int)dst[e]) >> BSHIFT], 1);
    __syncthreads();
    for (int i = tid; i < NB; i += 256) {
        int c = hist[i];
        base[i] = (c > 0) ? atomicAdd(&bucket_cnt[i], c) : 0;
    }
    __syncthreads();
    for (int e = lo + tid; e < hi; e += 256) {
        int d = dst[e];
        int s = __builtin_nontemporal_load(src + e);
        int bin = d >> BSHIFT;
        int r = base[bin] + atomicAdd(&cur[bin], 1);
        if (r < CAP) ebuf[bin * CAP + r] = s | ((d & 511) << 17);
    }
}

// ---------------- per-bucket node-level CSR, window staged in LDS, in-place sort ----------------
__global__ __launch_bounds__(512) void k_bucket_csr2(const int* __restrict__ bucket_cnt,
                                                     int* __restrict__ ebuf,
                                                     int* __restrict__ rowptr,
                                                     int* __restrict__ rowend) {
    __shared__ int stage[CAP];     // 72 KB
    __shared__ int cnt[512];       // counts -> inclusive scan
    __shared__ int cur[512];
    int b = blockIdx.x;
    int tid = threadIdx.x;
    int base = b * CAP;
    int n = min(bucket_cnt[b], CAP);
    cnt[tid] = 0;
    cur[tid] = 0;
    __syncthreads();
    for (int j = tid; j < n; j += 512) {
        int w = __builtin_nontemporal_load(ebuf + base + j);
        stage[j] = w;
        atomicAdd(&cnt[((unsigned int)w) >> 17], 1);
    }
    __syncthreads();
    int v = cnt[tid];
    int val = v;
    __syncthreads();
    cnt[tid] = val;
    __syncthreads();
#pragma unroll
    for (int o = 1; o < 512; o <<= 1) {
        int t = (tid >= o) ? cnt[tid - o] : 0;
        __syncthreads();
        val += t;
        cnt[tid] = val;
        __syncthreads();
    }
    int excl = val - v;
    int node = (b << BSHIFT) + tid;
    if (node < N_NODES) {
        rowptr[node] = base + excl;
        rowend[node] = base + val;
    }
    __syncthreads();
    for (int j = tid; j < n; j += 512) {
        int w = stage[j];
        int dl = ((unsigned int)w) >> 17;
        int off = (dl == 0) ? 0 : cnt[dl - 1];
        int r = atomicAdd(&cur[dl], 1);
        ebuf[base + off + r] = w & 0x1FFFF;
    }
}

// ---------------- cast f32 x [N][38] -> 3 slice tables [N][8],[N][8],[N][4] bf16 pairs ----------------
__global__ __launch_bounds__(256) void k_cast_slices(const float* __restrict__ in,
                                                     unsigned int* __restrict__ sA,
                                                     unsigned int* __restrict__ sB,
                                                     unsigned int* __restrict__ sC) {
    int i = blockIdx.x * 256 + threadIdx.x;
    if (i >= N_NODES * 20) return;
    int n = i / 20;
    int p = i - n * 20;
    unsigned int w = 0;
    if (p < 19) {
        float2 v = ((const float2*)in)[n * 19 + p];
        w = pack_bf2(v.x, v.y);
    }
    if (p < 8)       sA[n * 8 + p] = w;
    else if (p < 16) sB[n * 8 + p - 8] = w;
    else             sC[n * 4 + p - 16] = w;
}

// ---------------- quad gather: thread = (node, quad of 4 dwords = 8 bf16), 4-edge unroll ----------------
template<int NQ, int RSTRIDE, int ASTRIDE, int OFF>
__global__ __launch_bounds__(256) void k_gather_quad(const unsigned int* __restrict__ feat,
                                                     const int* __restrict__ rowptr,
                                                     const int* __restrict__ rowend,
                                                     const int* __restrict__ elist,
                                                     float* __restrict__ agg) {
    int idx = blockIdx.x * 256 + threadIdx.x;
    if (idx >= N_NODES * NQ) return;
    int n = idx / NQ;
    int q = idx - n * NQ;
    int j = rowptr[n];
    int e = rowend[n];
    const unsigned int* fq = feat + q * 4;
    float a0 = 0.f, a1 = 0.f, a2 = 0.f, a3 = 0.f, a4 = 0.f, a5 = 0.f, a6 = 0.f, a7 = 0.f;
    for (; j + 3 < e; j += 4) {
        int s0 = __builtin_nontemporal_load(elist + j);
        int s1 = __builtin_nontemporal_load(elist + j + 1);
        int s2 = __builtin_nontemporal_load(elist + j + 2);
        int s3 = __builtin_nontemporal_load(elist + j + 3);
        uint4 w0 = *(const uint4*)(fq + (size_t)s0 * RSTRIDE);
        uint4 w1 = *(const uint4*)(fq + (size_t)s1 * RSTRIDE);
        uint4 w2 = *(const uint4*)(fq + (size_t)s2 * RSTRIDE);
        uint4 w3 = *(const uint4*)(fq + (size_t)s3 * RSTRIDE);
        a0 += __uint_as_float(w0.x << 16);
        a1 += __uint_as_float(w0.x & 0xffff0000u);
        a2 += __uint_as_float(w0.y << 16);
        a3 += __uint_as_float(w0.y & 0xffff0000u);
        a4 += __uint_as_float(w0.z << 16);
        a5 += __uint_as_float(w0.z & 0xffff0000u);
        a6 += __uint_as_float(w0.w << 16);
        a7 += __uint_as_float(w0.w & 0xffff0000u);
        a0 += __uint_as_float(w1.x << 16);
        a1 += __uint_as_float(w1.x & 0xffff0000u);
        a2 += __uint_as_float(w1.y << 16);
        a3 += __uint_as_float(w1.y & 0xffff0000u);
        a4 += __uint_as_float(w1.z << 16);
        a5 += __uint_as_float(w1.z & 0xffff0000u);
        a6 += __uint_as_float(w1.w << 16);
        a7 += __uint_as_float(w1.w & 0xffff0000u);
        a0 += __uint_as_float(w2.x << 16);
        a1 += __uint_as_float(w2.x & 0xffff0000u);
        a2 += __uint_as_float(w2.y << 16);
        a3 += __uint_as_float(w2.y & 0xffff0000u);
        a4 += __uint_as_float(w2.z << 16);
        a5 += __uint_as_float(w2.z & 0xffff0000u);
        a6 += __uint_as_float(w2.w << 16);
        a7 += __uint_as_float(w2.w & 0xffff0000u);
        a0 += __uint_as_float(w3.x << 16);
        a1 += __uint_as_float(w3.x & 0xffff0000u);
        a2 += __uint_as_float(w3.y << 16);
        a3 += __uint_as_float(w3.y & 0xffff0000u);
        a4 += __uint_as_float(w3.z << 16);
        a5 += __uint_as_float(w3.z & 0xffff0000u);
        a6 += __uint_as_float(w3.w << 16);
        a7 += __uint_as_float(w3.w & 0xffff0000u);
    }
    for (; j < e; ++j) {
        int s = __builtin_nontemporal_load(elist + j);
        uint4 w = *(const uint4*)(fq + (size_t)s * RSTRIDE);
        a0 += __uint_as_float(w.x << 16);
        a1 += __uint_as_float(w.x & 0xffff0000u);
        a2 += __uint_as_float(w.y << 16);
        a3 += __uint_as_float(w.y & 0xffff0000u);
        a4 += __uint_as_float(w.z << 16);
        a5 += __uint_as_float(w.z & 0xffff0000u);
        a6 += __uint_as_float(w.w << 16);
        a7 += __uint_as_float(w.w & 0xffff0000u);
    }
    float* ao = agg + (size_t)n * ASTRIDE + OFF + q * 8;
    __builtin_nontemporal_store(a0, ao + 0);
    __builtin_nontemporal_store(a1, ao + 1);
    __builtin_nontemporal_store(a2, ao + 2);
    __builtin_nontemporal_store(a3, ao + 3);
    __builtin_nontemporal_store(a4, ao + 4);
    __builtin_nontemporal_store(a5, ao + 5);
    __builtin_nontemporal_store(a6, ao + 6);
    __builtin_nontemporal_store(a7, ao + 7);
}

// -------- fused layer0+layer1-dense (f16 dot2, node-pair sharing, lane-half split) --------
__global__ __launch_bounds__(256) void k_fused0(const float* __restrict__ agg,   // [N][40] (dims 0..37)
                                                const float* __restrict__ x,     // [N][38]
                                                const float* __restrict__ Wrel0,
                                                const float* __restrict__ b0,
                                                const float* __restrict__ Wroot0,
                                                const float* __restrict__ Wrel1,
                                                const float* __restrict__ b1,
                                                const float* __restrict__ Wroot1,
                                                unsigned int* __restrict__ y1b0, // [N][8] bf16 pairs (j 0..15)
                                                unsigned int* __restrict__ y1b1, // [N][8] bf16 pairs (j 16..31)
                                                float* __restrict__ r1) {        // [N][32]
    __shared__ unsigned int sWr[64 * 20];
    __shared__ unsigned int sWt[64 * 20];
    __shared__ unsigned int sW1r[32 * 32];
    __shared__ unsigned int sW1t[32 * 32];
    __shared__ float sb0[64];
    __shared__ float sb1[32];
    int tid = threadIdx.x;
    for (int i = tid; i < 64 * 20; i += 256) {
        int o = i / 20, d = i - o * 20;
        float a0 = (2 * d     < 38) ? Wrel0[o * 38 + 2 * d]     : 0.f;
        float a1 = (2 * d + 1 < 38) ? Wrel0[o * 38 + 2 * d + 1] : 0.f;
        float t0 = (2 * d     < 38) ? Wroot0[o * 38 + 2 * d]     : 0.f;
        float t1 = (2 * d + 1 < 38) ? Wroot0[o * 38 + 2 * d + 1] : 0.f;
        sWr[i] = mkh2(a0, a1);
        sWt[i] = mkh2(t0, t1);
    }
    for (int i = tid; i < 32 * 32; i += 256) {
        int op = i >> 5, j = i & 31;
        sW1r[i] = mkh2(Wrel1[j * 64 + 2 * op], Wrel1[j * 64 + 2 * op + 1]);
        sW1t[i] = mkh2(Wroot1[j * 64 + 2 * op], Wroot1[j * 64 + 2 * op + 1]);
    }
    if (tid < 64) sb0[tid] = b0[tid];
    if (tid < 32) sb1[tid] = b1[tid];
    __syncthreads();

    int lane = tid & 63;
    int ph = lane & 31;
    int sh = lane >> 5;
    int n0 = blockIdx.x * 256 + (tid >> 6) * 64 + 2 * ph;
    if (n0 >= N_NODES) return;
    int n1 = n0 + 1;

    unsigned int xa0[20], xx0[20], xa1[20], xx1[20];
    {
        const float2* A0 = (const float2*)(agg + (size_t)n0 * 40);
        const float2* X0 = (const float2*)(x   + (size_t)n0 * 38);
        const float2* A1 = (const float2*)(agg + (size_t)n1 * 40);
        const float2* X1 = (const float2*)(x   + (size_t)n1 * 38);
#pragma unroll
        for (int i = 0; i < 19; ++i) {
            float2 v;
            v = A0[i]; xa0[i] = mkh2(v.x, v.y);
            v = X0[i]; xx0[i] = mkh2(v.x, v.y);
            v = A1[i]; xa1[i] = mkh2(v.x, v.y);
            v = X1[i]; xx1[i] = mkh2(v.x, v.y);
        }
        xa0[19] = 0; xx0[19] = 0; xa1[19] = 0; xx1[19] = 0;
    }

    unsigned int hp0[16], hp1[16];
    int obase = sh * 32;
#pragma unroll
    for (int i = 0; i < 16; ++i) {
        float h00 = 0.f, h01 = 0.f, h10 = 0.f, h11 = 0.f;
#pragma unroll
        for (int par = 0; par < 2; ++par) {
            int o = obase + 2 * i + par;
            float c0 = sb0[o], c1 = 0.f, c2 = 0.f, c3 = 0.f;
            float d0 = sb0[o], d1 = 0.f, d2 = 0.f, d3 = 0.f;
            const uint4* wr = (const uint4*)(sWr + o * 20);
            const uint4* wt = (const uint4*)(sWt + o * 20);
#pragma unroll
            for (int q = 0; q < 5; ++q) {
                uint4 w = wr[q];
                c0 = fdot2f(u2h(xa0[4 * q + 0]), u2h(w.x), c0);
                c1 = fdot2f(u2h(xa0[4 * q + 1]), u2h(w.y), c1);
                c2 = fdot2f(u2h(xa0[4 * q + 2]), u2h(w.z), c2);
                c3 = fdot2f(u2h(xa0[4 * q + 3]), u2h(w.w), c3);
                d0 = fdot2f(u2h(xa1[4 * q + 0]), u2h(w.x), d0);
                d1 = fdot2f(u2h(xa1[4 * q + 1]), u2h(w.y), d1);
                d2 = fdot2f(u2h(xa1[4 * q + 2]), u2h(w.z), d2);
                d3 = fdot2f(u2h(xa1[4 * q + 3]), u2h(w.w), d3);
                uint4 v = wt[q];
                c0 = fdot2f(u2h(xx0[4 * q + 0]), u2h(v.x), c0);
                c1 = fdot2f(u2h(xx0[4 * q + 1]), u2h(v.y), c1);
                c2 = fdot2f(u2h(xx0[4 * q + 2]), u2h(v.z), c2);
                c3 = fdot2f(u2h(xx0[4 * q + 3]), u2h(v.w), c3);
                d0 = fdot2f(u2h(xx1[4 * q + 0]), u2h(v.x), d0);
                d1 = fdot2f(u2h(xx1[4 * q + 1]), u2h(v.y), d1);
                d2 = fdot2f(u2h(xx1[4 * q + 2]), u2h(v.z), d2);
                d3 = fdot2f(u2h(xx1[4 * q + 3]), u2h(v.w), d3);
            }
            float hA = fast_tanh(c0 + c1 + c2 + c3);
            float hB = fast_tanh(d0 + d1 + d2 + d3);
            if (par == 0) { h00 = hA; h10 = hB; }
            else          { h01 = hA; h11 = hB; }
        }
        hp0[i] = mkh2(h00, h01);
        hp1[i] = mkh2(h10, h11);
    }

    unsigned int H0[32], H1[32];
#pragma unroll
    for (int i = 0; i < 16; ++i) {
        unsigned int g0 = (unsigned int)__shfl_xor((int)hp0[i], 32);
        unsigned int g1 = (unsigned int)__shfl_xor((int)hp1[i], 32);
        if (sh == 0) { H0[i] = hp0[i]; H0[16 + i] = g0; H1[i] = hp1[i]; H1[16 + i] = g1; }
        else         { H0[i] = g0; H0[16 + i] = hp0[i]; H1[i] = g1; H1[16 + i] = hp1[i]; }
    }

    int jb = sh * 16;
    float y0[16], r0[16], y1v[16], r1v[16];
#pragma unroll
    for (int j = 0; j < 16; ++j) {
        y0[j] = 0.f; y1v[j] = 0.f;
        float bb = sb1[jb + j];
        r0[j] = bb; r1v[j] = bb;
    }
#pragma unroll
    for (int op = 0; op < 32; ++op) {
        f16x2 h0 = u2h(H0[op]);
        f16x2 h1 = u2h(H1[op]);
        const uint4* w1 = (const uint4*)(sW1r + op * 32 + jb);
        const uint4* w2 = (const uint4*)(sW1t + op * 32 + jb);
#pragma unroll
        for (int q = 0; q < 4; ++q) {
            uint4 a = w1[q], b = w2[q];
            y0[4 * q + 0] = fdot2f(h0, u2h(a.x), y0[4 * q + 0]);
            y0[4 * q + 1] = fdot2f(h0, u2h(a.y), y0[4 * q + 1]);
            y0[4 * q + 2] = fdot2f(h0, u2h(a.z), y0[4 * q + 2]);
            y0[4 * q + 3] = fdot2f(h0, u2h(a.w), y0[4 * q + 3]);
            y1v[4 * q + 0] = fdot2f(h1, u2h(a.x), y1v[4 * q + 0]);
            y1v[4 * q + 1] = fdot2f(h1, u2h(a.y), y1v[4 * q + 1]);
            y1v[4 * q + 2] = fdot2f(h1, u2h(a.z), y1v[4 * q + 2]);
            y1v[4 * q + 3] = fdot2f(h1, u2h(a.w), y1v[4 * q + 3]);
            r0[4 * q + 0] = fdot2f(h0, u2h(b.x), r0[4 * q + 0]);
            r0[4 * q + 1] = fdot2f(h0, u2h(b.y), r0[4 * q + 1]);
            r0[4 * q + 2] = fdot2f(h0, u2h(b.z), r0[4 * q + 2]);
            r0[4 * q + 3] = fdot2f(h0, u2h(b.w), r0[4 * q + 3]);
            r1v[4 * q + 0] = fdot2f(h1, u2h(b.x), r1v[4 * q + 0]);
            r1v[4 * q + 1] = fdot2f(h1, u2h(b.y), r1v[4 * q + 1]);
            r1v[4 * q + 2] = fdot2f(h1, u2h(b.z), r1v[4 * q + 2]);
            r1v[4 * q + 3] = fdot2f(h1, u2h(b.w), r1v[4 * q + 3]);
        }
    }

    unsigned int* yo0 = (sh ? y1b1 : y1b0) + (size_t)n0 * 8;
    unsigned int* yo1 = (sh ? y1b1 : y1b0) + (size_t)n1 * 8;
#pragma unroll
    for (int p = 0; p < 8; ++p) {
        yo0[p] = pack_bf2(y0[2 * p], y0[2 * p + 1]);
        yo1[p] = pack_bf2(y1v[2 * p], y1v[2 * p + 1]);
    }
    float4* ro0 = (float4*)(r1 + (size_t)n0 * 32 + jb);
    float4* ro1 = (float4*)(r1 + (size_t)n1 * 32 + jb);
#pragma unroll
    for (int q = 0; q < 4; ++q) {
        ro0[q] = make_float4(r0[4 * q], r0[4 * q + 1], r0[4 * q + 2], r0[4 * q + 3]);
        ro1[q] = make_float4(r1v[4 * q], r1v[4 * q + 1], r1v[4 * q + 2], r1v[4 * q + 3]);
    }
}

// -------- fused layer1-finish + layer2-rel --------
__global__ __launch_bounds__(256) void k_fused1(const float* __restrict__ agg,   // [N][32]
                                                const float* __restrict__ r1,    // [N][32]
                                                const float* __restrict__ Wrel2, // [16][32]
                                                float* __restrict__ h2,          // [N][32]
                                                unsigned int* __restrict__ y2b)  // [N][8]
{
    __shared__ float sW[32 * 16];
    int tid = threadIdx.x;
    for (int i = tid; i < 512; i += 256) {
        int k = i >> 4, j = i & 15;
        sW[i] = Wrel2[j * 32 + k];
    }
    __syncthreads();
    int n = blockIdx.x * 256 + tid;
    if (n >= N_NODES) return;
    const float4* a4 = (const float4*)(agg + (size_t)n * 32);
    const float4* r4 = (const float4*)(r1 + (size_t)n * 32);
    float h[32];
#pragma unroll
    for (int i = 0; i < 8; ++i) {
        float4 a = a4[i], r = r4[i];
        h[4 * i]     = fast_tanh(a.x + r.x);
        h[4 * i + 1] = fast_tanh(a.y + r.y);
        h[4 * i + 2] = fast_tanh(a.z + r.z);
        h[4 * i + 3] = fast_tanh(a.w + r.w);
    }
    float4* ho = (float4*)(h2 + (size_t)n * 32);
#pragma unroll
    for (int i = 0; i < 8; ++i) ho[i] = make_float4(h[4 * i], h[4 * i + 1], h[4 * i + 2], h[4 * i + 3]);
    float y[16];
#pragma unroll
    for (int j = 0; j < 16; ++j) y[j] = 0.f;
#pragma unroll
    for (int k = 0; k < 32; ++k) {
        const float4* w = (const float4*)(sW + k * 16);
#pragma unroll
        for (int j = 0; j < 4; ++j) {
            float4 wv = w[j];
            y[4 * j]     += h[k] * wv.x; y[4 * j + 1] += h[k] * wv.y;
            y[4 * j + 2] += h[k] * wv.z; y[4 * j + 3] += h[k] * wv.w;
        }
    }
    unsigned int* yo = y2b + (size_t)n * 8;
#pragma unroll
    for (int p = 0; p < 8; ++p) yo[p] = pack_bf2(y[2 * p], y[2 * p + 1]);
}

// -------- graph boundaries from sorted batch vector --------
__global__ __launch_bounds__(256) void k_graph_start(const int* __restrict__ batch,
                                                     int* __restrict__ gstart) {
    int i = blockIdx.x * 256 + threadIdx.x;
    if (i >= N_NODES) return;
    int g = batch[i];
    int gp = (i == 0) ? -1 : batch[i - 1];
    for (int gg = gp + 1; gg <= g; ++gg) gstart[gg] = i;
    if (i == N_NODES - 1)
        for (int gg = g + 1; gg <= N_GRAPHS; ++gg) gstart[gg] = N_NODES;
}

// -------- per-graph sums of agg[16] and h2[32], no atomics (batch sorted) --------
__global__ __launch_bounds__(256) void k_pool(const float* __restrict__ agg,   // [N][16]
                                              const float* __restrict__ h2,    // [N][32]
                                              const int* __restrict__ gstart,
                                              float* __restrict__ psum)        // [G][48]
{
    __shared__ float part[4][48];
    int g = blockIdx.x;
    int wave = threadIdx.x >> 6;
    int lane = threadIdx.x & 63;
    int s = gstart[g], e = gstart[g + 1];
    if (lane < 48) {
        float a0 = 0.f, a1 = 0.f;
        if (lane < 16) {
            int n = s + wave;
            for (; n + 4 < e; n += 8) {
                a0 += agg[n * 16 + lane];
                a1 += agg[(n + 4) * 16 + lane];
            }
            if (n < e) a0 += agg[n * 16 + lane];
        } else {
            int d = lane - 16;
            int n = s + wave;
            for (; n + 4 < e; n += 8) {
                a0 += h2[n * 32 + d];
                a1 += h2[(n + 4) * 32 + d];
            }
            if (n < e) a0 += h2[n * 32 + d];
        }
        part[wave][lane] = a0 + a1;
    }
    __syncthreads();
    if (threadIdx.x < 48)
        psum[g * 48 + threadIdx.x] = part[0][threadIdx.x] + part[1][threadIdx.x]
                                   + part[2][threadIdx.x] + part[3][threadIdx.x];
}

// -------- finalize --------
__global__ __launch_bounds__(256) void k_finalize2(const float* __restrict__ psum,  // [G][48]
                                                   const float* __restrict__ Wroot, // [16][32]
                                                   const float* __restrict__ b,
                                                   const int* __restrict__ gstart,
                                                   float* __restrict__ out) {
    __shared__ float sW[16 * 32];
    __shared__ float sb[16];
    int tid = threadIdx.x;
    for (int i = tid; i < 16 * 32; i += 256) sW[i] = Wroot[i];
    if (tid < 16) sb[tid] = b[tid];
    __syncthreads();
    int idx = blockIdx.x * 256 + tid;   // (g, o)
    if (idx >= N_GRAPHS * 16) return;
    int g = idx >> 4;
    int o = idx & 15;
    float cnt = (float)(gstart[g + 1] - gstart[g]);
    const float* p = psum + g * 48;
    float acc = p[o] + cnt * sb[o];
#pragma unroll
    for (int k = 0; k < 32; ++k) acc += p[16 + k] * sW[o * 32 + k];
    out[idx] = fast_tanh(acc / fmaxf(cnt, 1.f));
}

extern "C" void kernel_launch(void* const* d_in, const int* in_sizes, int n_in,
                              void* d_out, int out_size, void* d_ws, size_t ws_size,
                              hipStream_t stream) {
    const float* x      = (const float*)d_in[0];
    const int*   eidx   = (const int*)d_in[1];
    const int*   src    = eidx;
    const int*   dst    = eidx + N_EDGES;
    const int*   batch  = (const int*)d_in[2];
    const float* Wrel0  = (const float*)d_in[3];
    const float* b0     = (const float*)d_in[4];
    const float* Wroot0 = (const float*)d_in[5];
    const float* Wrel1  = (const float*)d_in[6];
    const float* b1     = (const float*)d_in[7];
    const float* Wroot1 = (const float*)d_in[8];
    const float* Wrel2  = (const float*)d_in[9];
    const float* b2     = (const float*)d_in[10];
    const float* Wroot2 = (const float*)d_in[11];
    float* out = (float*)d_out;

    // ---- workspace layout ----
    float* ws   = (float*)d_ws;
    float* agg  = ws;                                  // N*40 f32 (stride 40; reused 40/32/16)
    float* r1   = agg + (size_t)N_NODES * 40;          // N*32 f32 (alias: x slice tables before fused0)
    float* h2   = r1  + (size_t)N_NODES * 32;          // N*32 f32
    unsigned int* ybuf = (unsigned int*)(h2 + (size_t)N_NODES * 32); // N*16 uints
    float* psum = (float*)(ybuf + (size_t)N_NODES * 16);             // 256*48
    int* rowptr      = (int*)(psum + N_GRAPHS * 48);   // N
    int* rowend      = rowptr + N_NODES;               // N
    int* gstart      = rowend + N_NODES;               // 257 (pad 260)
    int* bucket_cnt  = gstart + 260;                   // NB (pad 400)
    int* ebuf        = bucket_cnt + 400;               // NB*CAP (~14.5 MB), becomes node-sorted elist
    // x slice tables alias r1 (8+8+4 = 20 dwords/node)
    unsigned int* xbA = (unsigned int*)r1;             // [N][8]  (3.2 MB)
    unsigned int* xbB = xbA + (size_t)N_NODES * 8;     // [N][8]  (3.2 MB)
    unsigned int* xbC = xbB + (size_t)N_NODES * 8;     // [N][4]  (1.6 MB)
    unsigned int* y1b0 = ybuf;                         // [N][8]
    unsigned int* y1b1 = ybuf + (size_t)N_NODES * 8;   // [N][8]
    unsigned int* y2b  = ybuf;                         // [N][8] (y1b0 dead after L1 gather A)

    // ---- cast x to 3 slice tables ----
    k_cast_slices<<<(N_NODES * 20 + 255) / 256, 256, 0, stream>>>(x, xbA, xbB, xbC);

    // ---- CSR build (fused scatter + LDS-staged per-bucket node sort) + graph boundaries ----
    hipMemsetAsync(bucket_cnt, 0, sizeof(int) * NB, stream);
    k_scatter2<<<NBLK, 256, 0, stream>>>(src, dst, bucket_cnt, ebuf);
    k_bucket_csr2<<<NB, 512, 0, stream>>>(bucket_cnt, ebuf, rowptr, rowend);
    k_graph_start<<<(N_NODES + 255) / 256, 256, 0, stream>>>(batch, gstart);

    // ---- Layer 0: 3 L2-resident slice passes (quad loads), then fused dense ----
    k_gather_quad<2, 8, 40, 0 ><<<(N_NODES * 2 + 255) / 256, 256, 0, stream>>>(xbA, rowptr, rowend, ebuf, agg);
    k_gather_quad<2, 8, 40, 16><<<(N_NODES * 2 + 255) / 256, 256, 0, stream>>>(xbB, rowptr, rowend, ebuf, agg);
    k_gather_quad<1, 4, 40, 32><<<(N_NODES * 1 + 255) / 256, 256, 0, stream>>>(xbC, rowptr, rowend, ebuf, agg);
    k_fused0<<<(N_NODES + 255) / 256, 256, 0, stream>>>(agg, x, Wrel0, b0, Wroot0,
                                                        Wrel1, b1, Wroot1, y1b0, y1b1, r1);

    // ---- Layer 1: 2 slice passes, then fused finish + layer2-rel ----
    k_gather_quad<2, 8, 32, 0 ><<<(N_NODES * 2 + 255) / 256, 256, 0, stream>>>(y1b0, rowptr, rowend, ebuf, agg);
    k_gather_quad<2, 8, 32, 16><<<(N_NODES * 2 + 255) / 256, 256, 0, stream>>>(y1b1, rowptr, rowend, ebuf, agg);
    k_fused1<<<(N_NODES + 255) / 256, 256, 0, stream>>>(agg, r1, Wrel2, h2, y2b);

    // ---- Layer 2: single slice pass (table 3.2 MB) ----
    k_gather_quad<2, 8, 16, 0 ><<<(N_NODES * 2 + 255) / 256, 256, 0, stream>>>(y2b, rowptr, rowend, ebuf, agg);

    // ---- pool + finalize ----
    k_pool<<<N_GRAPHS, 256, 0, stream>>>(agg, h2, gstart, psum);
    k_finalize2<<<(N_GRAPHS * 16 + 255) / 256, 256, 0, stream>>>(psum, Wroot2, b2, gstart, out);
}

// Round 16
// 339.386 us; speedup vs baseline: 1.3339x; 1.3339x over previous
//
#include <hip/hip_runtime.h>
#include <math.h>

#define N_NODES  100000
#define N_EDGES  3200000
#define N_GRAPHS 256

// DIMS = [38, 64, 32, 16]

#define BSHIFT 9
#define NB 196                                   // buckets of 512 nodes
#define CAP 18432                                // bucket window capacity (mean 16384, +16 sigma)
#define NBLK 640
#define EPB ((N_EDGES + NBLK - 1) / NBLK)        // 5000 edges per block

typedef _Float16 f16;
typedef _Float16 f16x2 __attribute__((ext_vector_type(2)));

__device__ __forceinline__ float fast_tanh(float x) {
    x = fminf(20.f, fmaxf(-20.f, x));
    float e = __expf(2.f * x);
    return (e - 1.f) / (e + 1.f);
}

// pack two f32 -> bf16x2 (RNE)
__device__ __forceinline__ unsigned int pack_bf2(float a, float b) {
    unsigned int ua = __float_as_uint(a);
    unsigned int ub = __float_as_uint(b);
    ua += 0x7fffu + ((ua >> 16) & 1u);
    ub += 0x7fffu + ((ub >> 16) & 1u);
    return (ua >> 16) | (ub & 0xffff0000u);
}

__device__ __forceinline__ f16x2 u2h(unsigned int u) { union { unsigned int u; f16x2 h; } c; c.u = u; return c.h; }
__device__ __forceinline__ unsigned int h2u(f16x2 h) { union { unsigned int u; f16x2 h; } c; c.h = h; return c.u; }
__device__ __forceinline__ unsigned int mkh2(float a, float b) {
    f16x2 v; v.x = (f16)a; v.y = (f16)b; return h2u(v);
}

__device__ __forceinline__ float fdot2f(f16x2 a, f16x2 b, float c) {
#if __has_builtin(__builtin_amdgcn_fdot2)
    return __builtin_amdgcn_fdot2(a, b, c, false);
#else
    return c + (float)a.x * (float)b.x + (float)a.y * (float)b.y;
#endif
}

// ---------------- fused bucket scatter: count -> reserve -> write (fixed windows) ----------------
__global__ __launch_bounds__(256) void k_scatter2(const int* __restrict__ src,
                                                  const int* __restrict__ dst,
                                                  int* __restrict__ bucket_cnt,
                                                  int* __restrict__ ebuf) {
    __shared__ int hist[NB];
    __shared__ int base[NB];
    __shared__ int cur[NB];
    int tid = threadIdx.x, b = blockIdx.x;
    for (int i = tid; i < NB; i += 256) { hist[i] = 0; cur[i] = 0; }
    __syncthreads();
    int lo = b * EPB, hi = min(lo + EPB, N_EDGES);
    for (int e = lo + tid; e < hi; e += 256)
        atomicAdd(&hist[((unsigned int)dst[e]) >> BSHIFT], 1);
    __syncthreads();
    for (int i = tid; i < NB; i += 256) {
        int c = hist[i];
        base[i] = (c > 0) ? atomicAdd(&bucket_cnt[i], c) : 0;
    }
    __syncthreads();
    for (int e = lo + tid; e < hi; e += 256) {
        int d = dst[e];
        int bin = d >> BSHIFT;
        int r = base[bin] + atomicAdd(&cur[bin], 1);
        if (r < CAP) ebuf[bin * CAP + r] = src[e] | ((d & 511) << 17);
    }
}

// ---------------- per-bucket node-level CSR, window staged in LDS, in-place sort ----------------
__global__ __launch_bounds__(512) void k_bucket_csr2(const int* __restrict__ bucket_cnt,
                                                     int* __restrict__ ebuf,
                                                     int* __restrict__ rowptr,
                                                     int* __restrict__ rowend) {
    __shared__ int stage[CAP];     // 72 KB
    __shared__ int cnt[512];       // counts -> inclusive scan
    __shared__ int cur[512];
    int b = blockIdx.x;
    int tid = threadIdx.x;
    int base = b * CAP;
    int n = min(bucket_cnt[b], CAP);
    cnt[tid] = 0;
    cur[tid] = 0;
    __syncthreads();
    for (int j = tid; j < n; j += 512) {
        int w = ebuf[base + j];
        stage[j] = w;
        atomicAdd(&cnt[((unsigned int)w) >> 17], 1);
    }
    __syncthreads();
    int v = cnt[tid];
    int val = v;
    __syncthreads();
    cnt[tid] = val;
    __syncthreads();
#pragma unroll
    for (int o = 1; o < 512; o <<= 1) {
        int t = (tid >= o) ? cnt[tid - o] : 0;
        __syncthreads();
        val += t;
        cnt[tid] = val;
        __syncthreads();
    }
    // cnt[tid] = inclusive prefix sum; exclusive = val - v = cnt[tid-1]
    int excl = val - v;
    int node = (b << BSHIFT) + tid;
    if (node < N_NODES) {
        rowptr[node] = base + excl;
        rowend[node] = base + val;
    }
    __syncthreads();
    for (int j = tid; j < n; j += 512) {
        int w = stage[j];
        int dl = ((unsigned int)w) >> 17;
        int off = (dl == 0) ? 0 : cnt[dl - 1];
        int r = atomicAdd(&cur[dl], 1);
        ebuf[base + off + r] = w & 0x1FFFF;
    }
}

// ---------------- cast f32 x [N][38] -> bf16-pair table [N][20] (word 19 = 0) ----------------
__global__ __launch_bounds__(256) void k_cast_pad(const float* __restrict__ in,
                                                  unsigned int* __restrict__ out) {
    int i = blockIdx.x * 256 + threadIdx.x;
    if (i >= N_NODES * 20) return;
    int n = i / 20;
    int p = i - n * 20;
    unsigned int w = 0;
    if (p < 19) {
        float2 v = ((const float2*)in)[n * 19 + p];
        w = pack_bf2(v.x, v.y);
    }
    out[i] = w;
}

// ---------------- quad gather: thread = (node, quad of 4 dwords = 8 bf16) ----------------
template<int NQ, int RSTRIDE, int ASTRIDE>
__global__ __launch_bounds__(256) void k_gather_quad(const unsigned int* __restrict__ feat,
                                                     const int* __restrict__ rowptr,
                                                     const int* __restrict__ rowend,
                                                     const int* __restrict__ elist,
                                                     float* __restrict__ agg) {
    int idx = blockIdx.x * 256 + threadIdx.x;
    if (idx >= N_NODES * NQ) return;
    int n = idx / NQ;
    int q = idx - n * NQ;
    int j = rowptr[n];
    int e = rowend[n];
    const unsigned int* fq = feat + q * 4;
    float a0 = 0.f, a1 = 0.f, a2 = 0.f, a3 = 0.f, a4 = 0.f, a5 = 0.f, a6 = 0.f, a7 = 0.f;
    for (; j + 1 < e; j += 2) {
        int s0 = elist[j];
        int s1 = elist[j + 1];
        uint4 w0 = *(const uint4*)(fq + (size_t)s0 * RSTRIDE);
        uint4 w1 = *(const uint4*)(fq + (size_t)s1 * RSTRIDE);
        a0 += __uint_as_float(w0.x << 16);
        a1 += __uint_as_float(w0.x & 0xffff0000u);
        a2 += __uint_as_float(w0.y << 16);
        a3 += __uint_as_float(w0.y & 0xffff0000u);
        a4 += __uint_as_float(w0.z << 16);
        a5 += __uint_as_float(w0.z & 0xffff0000u);
        a6 += __uint_as_float(w0.w << 16);
        a7 += __uint_as_float(w0.w & 0xffff0000u);
        a0 += __uint_as_float(w1.x << 16);
        a1 += __uint_as_float(w1.x & 0xffff0000u);
        a2 += __uint_as_float(w1.y << 16);
        a3 += __uint_as_float(w1.y & 0xffff0000u);
        a4 += __uint_as_float(w1.z << 16);
        a5 += __uint_as_float(w1.z & 0xffff0000u);
        a6 += __uint_as_float(w1.w << 16);
        a7 += __uint_as_float(w1.w & 0xffff0000u);
    }
    if (j < e) {
        uint4 w = *(const uint4*)(fq + (size_t)elist[j] * RSTRIDE);
        a0 += __uint_as_float(w.x << 16);
        a1 += __uint_as_float(w.x & 0xffff0000u);
        a2 += __uint_as_float(w.y << 16);
        a3 += __uint_as_float(w.y & 0xffff0000u);
        a4 += __uint_as_float(w.z << 16);
        a5 += __uint_as_float(w.z & 0xffff0000u);
        a6 += __uint_as_float(w.w << 16);
        a7 += __uint_as_float(w.w & 0xffff0000u);
    }
    float4* ao = (float4*)(agg + (size_t)n * ASTRIDE + q * 8);
    ao[0] = make_float4(a0, a1, a2, a3);
    ao[1] = make_float4(a4, a5, a6, a7);
}

// -------- fused layer0+layer1-dense (f16 dot2, node-pair sharing, lane-half split) --------
__global__ __launch_bounds__(256) void k_fused0(const float* __restrict__ agg,   // [N][40] (dims 0..37)
                                                const float* __restrict__ x,     // [N][38]
                                                const float* __restrict__ Wrel0,
                                                const float* __restrict__ b0,
                                                const float* __restrict__ Wroot0,
                                                const float* __restrict__ Wrel1,
                                                const float* __restrict__ b1,
                                                const float* __restrict__ Wroot1,
                                                unsigned int* __restrict__ y1b,  // [N][16] bf16 pairs
                                                float* __restrict__ r1) {        // [N][32]
    __shared__ unsigned int sWr[64 * 20];
    __shared__ unsigned int sWt[64 * 20];
    __shared__ unsigned int sW1r[32 * 32];
    __shared__ unsigned int sW1t[32 * 32];
    __shared__ float sb0[64];
    __shared__ float sb1[32];
    int tid = threadIdx.x;
    for (int i = tid; i < 64 * 20; i += 256) {
        int o = i / 20, d = i - o * 20;
        float a0 = (2 * d     < 38) ? Wrel0[o * 38 + 2 * d]     : 0.f;
        float a1 = (2 * d + 1 < 38) ? Wrel0[o * 38 + 2 * d + 1] : 0.f;
        float t0 = (2 * d     < 38) ? Wroot0[o * 38 + 2 * d]     : 0.f;
        float t1 = (2 * d + 1 < 38) ? Wroot0[o * 38 + 2 * d + 1] : 0.f;
        sWr[i] = mkh2(a0, a1);
        sWt[i] = mkh2(t0, t1);
    }
    for (int i = tid; i < 32 * 32; i += 256) {
        int op = i >> 5, j = i & 31;
        sW1r[i] = mkh2(Wrel1[j * 64 + 2 * op], Wrel1[j * 64 + 2 * op + 1]);
        sW1t[i] = mkh2(Wroot1[j * 64 + 2 * op], Wroot1[j * 64 + 2 * op + 1]);
    }
    if (tid < 64) sb0[tid] = b0[tid];
    if (tid < 32) sb1[tid] = b1[tid];
    __syncthreads();

    int lane = tid & 63;
    int ph = lane & 31;
    int sh = lane >> 5;
    int n0 = blockIdx.x * 256 + (tid >> 6) * 64 + 2 * ph;
    if (n0 >= N_NODES) return;
    int n1 = n0 + 1;

    unsigned int xa0[20], xx0[20], xa1[20], xx1[20];
    {
        const float2* A0 = (const float2*)(agg + (size_t)n0 * 40);
        const float2* X0 = (const float2*)(x   + (size_t)n0 * 38);
        const float2* A1 = (const float2*)(agg + (size_t)n1 * 40);
        const float2* X1 = (const float2*)(x   + (size_t)n1 * 38);
#pragma unroll
        for (int i = 0; i < 19; ++i) {
            float2 v;
            v = A0[i]; xa0[i] = mkh2(v.x, v.y);
            v = X0[i]; xx0[i] = mkh2(v.x, v.y);
            v = A1[i]; xa1[i] = mkh2(v.x, v.y);
            v = X1[i]; xx1[i] = mkh2(v.x, v.y);
        }
        xa0[19] = 0; xx0[19] = 0; xa1[19] = 0; xx1[19] = 0;
    }

    unsigned int hp0[16], hp1[16];
    int obase = sh * 32;
#pragma unroll
    for (int i = 0; i < 16; ++i) {
        float h00 = 0.f, h01 = 0.f, h10 = 0.f, h11 = 0.f;
#pragma unroll
        for (int par = 0; par < 2; ++par) {
            int o = obase + 2 * i + par;
            float c0 = sb0[o], c1 = 0.f, c2 = 0.f, c3 = 0.f;
            float d0 = sb0[o], d1 = 0.f, d2 = 0.f, d3 = 0.f;
            const uint4* wr = (const uint4*)(sWr + o * 20);
            const uint4* wt = (const uint4*)(sWt + o * 20);
#pragma unroll
            for (int q = 0; q < 5; ++q) {
                uint4 w = wr[q];
                c0 = fdot2f(u2h(xa0[4 * q + 0]), u2h(w.x), c0);
                c1 = fdot2f(u2h(xa0[4 * q + 1]), u2h(w.y), c1);
                c2 = fdot2f(u2h(xa0[4 * q + 2]), u2h(w.z), c2);
                c3 = fdot2f(u2h(xa0[4 * q + 3]), u2h(w.w), c3);
                d0 = fdot2f(u2h(xa1[4 * q + 0]), u2h(w.x), d0);
                d1 = fdot2f(u2h(xa1[4 * q + 1]), u2h(w.y), d1);
                d2 = fdot2f(u2h(xa1[4 * q + 2]), u2h(w.z), d2);
                d3 = fdot2f(u2h(xa1[4 * q + 3]), u2h(w.w), d3);
                uint4 v = wt[q];
                c0 = fdot2f(u2h(xx0[4 * q + 0]), u2h(v.x), c0);
                c1 = fdot2f(u2h(xx0[4 * q + 1]), u2h(v.y), c1);
                c2 = fdot2f(u2h(xx0[4 * q + 2]), u2h(v.z), c2);
                c3 = fdot2f(u2h(xx0[4 * q + 3]), u2h(v.w), c3);
                d0 = fdot2f(u2h(xx1[4 * q + 0]), u2h(v.x), d0);
                d1 = fdot2f(u2h(xx1[4 * q + 1]), u2h(v.y), d1);
                d2 = fdot2f(u2h(xx1[4 * q + 2]), u2h(v.z), d2);
                d3 = fdot2f(u2h(xx1[4 * q + 3]), u2h(v.w), d3);
            }
            float hA = fast_tanh(c0 + c1 + c2 + c3);
            float hB = fast_tanh(d0 + d1 + d2 + d3);
            if (par == 0) { h00 = hA; h10 = hB; }
            else          { h01 = hA; h11 = hB; }
        }
        hp0[i] = mkh2(h00, h01);
        hp1[i] = mkh2(h10, h11);
    }

    unsigned int H0[32], H1[32];
#pragma unroll
    for (int i = 0; i < 16; ++i) {
        unsigned int g0 = (unsigned int)__shfl_xor((int)hp0[i], 32);
        unsigned int g1 = (unsigned int)__shfl_xor((int)hp1[i], 32);
        if (sh == 0) { H0[i] = hp0[i]; H0[16 + i] = g0; H1[i] = hp1[i]; H1[16 + i] = g1; }
        else         { H0[i] = g0; H0[16 + i] = hp0[i]; H1[i] = g1; H1[16 + i] = hp1[i]; }
    }

    int jb = sh * 16;
    float y0[16], r0[16], y1v[16], r1v[16];
#pragma unroll
    for (int j = 0; j < 16; ++j) {
        y0[j] = 0.f; y1v[j] = 0.f;
        float bb = sb1[jb + j];
        r0[j] = bb; r1v[j] = bb;
    }
#pragma unroll
    for (int op = 0; op < 32; ++op) {
        f16x2 h0 = u2h(H0[op]);
        f16x2 h1 = u2h(H1[op]);
        const uint4* w1 = (const uint4*)(sW1r + op * 32 + jb);
        const uint4* w2 = (const uint4*)(sW1t + op * 32 + jb);
#pragma unroll
        for (int q = 0; q < 4; ++q) {
            uint4 a = w1[q], b = w2[q];
            y0[4 * q + 0] = fdot2f(h0, u2h(a.x), y0[4 * q + 0]);
            y0[4 * q + 1] = fdot2f(h0, u2h(a.y), y0[4 * q + 1]);
            y0[4 * q + 2] = fdot2f(h0, u2h(a.z), y0[4 * q + 2]);
            y0[4 * q + 3] = fdot2f(h0, u2h(a.w), y0[4 * q + 3]);
            y1v[4 * q + 0] = fdot2f(h1, u2h(a.x), y1v[4 * q + 0]);
            y1v[4 * q + 1] = fdot2f(h1, u2h(a.y), y1v[4 * q + 1]);
            y1v[4 * q + 2] = fdot2f(h1, u2h(a.z), y1v[4 * q + 2]);
            y1v[4 * q + 3] = fdot2f(h1, u2h(a.w), y1v[4 * q + 3]);
            r0[4 * q + 0] = fdot2f(h0, u2h(b.x), r0[4 * q + 0]);
            r0[4 * q + 1] = fdot2f(h0, u2h(b.y), r0[4 * q + 1]);
            r0[4 * q + 2] = fdot2f(h0, u2h(b.z), r0[4 * q + 2]);
            r0[4 * q + 3] = fdot2f(h0, u2h(b.w), r0[4 * q + 3]);
            r1v[4 * q + 0] = fdot2f(h1, u2h(b.x), r1v[4 * q + 0]);
            r1v[4 * q + 1] = fdot2f(h1, u2h(b.y), r1v[4 * q + 1]);
            r1v[4 * q + 2] = fdot2f(h1, u2h(b.z), r1v[4 * q + 2]);
            r1v[4 * q + 3] = fdot2f(h1, u2h(b.w), r1v[4 * q + 3]);
        }
    }

    unsigned int* yo0 = y1b + (size_t)n0 * 16 + 8 * sh;
    unsigned int* yo1 = y1b + (size_t)n1 * 16 + 8 * sh;
#pragma unroll
    for (int p = 0; p < 8; ++p) {
        yo0[p] = pack_bf2(y0[2 * p], y0[2 * p + 1]);
        yo1[p] = pack_bf2(y1v[2 * p], y1v[2 * p + 1]);
    }
    float4* ro0 = (float4*)(r1 + (size_t)n0 * 32 + jb);
    float4* ro1 = (float4*)(r1 + (size_t)n1 * 32 + jb);
#pragma unroll
    for (int q = 0; q < 4; ++q) {
        ro0[q] = make_float4(r0[4 * q], r0[4 * q + 1], r0[4 * q + 2], r0[4 * q + 3]);
        ro1[q] = make_float4(r1v[4 * q], r1v[4 * q + 1], r1v[4 * q + 2], r1v[4 * q + 3]);
    }
}

// -------- fused layer1-finish + layer2-rel --------
__global__ __launch_bounds__(256) void k_fused1(const float* __restrict__ agg,   // [N][32]
                                                const float* __restrict__ r1,    // [N][32]
                                                const float* __restrict__ Wrel2, // [16][32]
                                                float* __restrict__ h2,          // [N][32]
                                                unsigned int* __restrict__ y2b)  // [N][8]
{
    __shared__ float sW[32 * 16];
    int tid = threadIdx.x;
    for (int i = tid; i < 512; i += 256) {
        int k = i >> 4, j = i & 15;
        sW[i] = Wrel2[j * 32 + k];
    }
    __syncthreads();
    int n = blockIdx.x * 256 + tid;
    if (n >= N_NODES) return;
    const float4* a4 = (const float4*)(agg + (size_t)n * 32);
    const float4* r4 = (const float4*)(r1 + (size_t)n * 32);
    float h[32];
#pragma unroll
    for (int i = 0; i < 8; ++i) {
        float4 a = a4[i], r = r4[i];
        h[4 * i]     = fast_tanh(a.x + r.x);
        h[4 * i + 1] = fast_tanh(a.y + r.y);
        h[4 * i + 2] = fast_tanh(a.z + r.z);
        h[4 * i + 3] = fast_tanh(a.w + r.w);
    }
    float4* ho = (float4*)(h2 + (size_t)n * 32);
#pragma unroll
    for (int i = 0; i < 8; ++i) ho[i] = make_float4(h[4 * i], h[4 * i + 1], h[4 * i + 2], h[4 * i + 3]);
    float y[16];
#pragma unroll
    for (int j = 0; j < 16; ++j) y[j] = 0.f;
#pragma unroll
    for (int k = 0; k < 32; ++k) {
        const float4* w = (const float4*)(sW + k * 16);
#pragma unroll
        for (int j = 0; j < 4; ++j) {
            float4 wv = w[j];
            y[4 * j]     += h[k] * wv.x; y[4 * j + 1] += h[k] * wv.y;
            y[4 * j + 2] += h[k] * wv.z; y[4 * j + 3] += h[k] * wv.w;
        }
    }
    unsigned int* yo = y2b + (size_t)n * 8;
#pragma unroll
    for (int p = 0; p < 8; ++p) yo[p] = pack_bf2(y[2 * p], y[2 * p + 1]);
}

// -------- graph boundaries from sorted batch vector --------
__global__ __launch_bounds__(256) void k_graph_start(const int* __restrict__ batch,
                                                     int* __restrict__ gstart) {
    int i = blockIdx.x * 256 + threadIdx.x;
    if (i >= N_NODES) return;
    int g = batch[i];
    int gp = (i == 0) ? -1 : batch[i - 1];
    for (int gg = gp + 1; gg <= g; ++gg) gstart[gg] = i;
    if (i == N_NODES - 1)
        for (int gg = g + 1; gg <= N_GRAPHS; ++gg) gstart[gg] = N_NODES;
}

// -------- per-graph sums of agg[16] and h2[32], no atomics (batch sorted) --------
__global__ __launch_bounds__(256) void k_pool(const float* __restrict__ agg,   // [N][16]
                                              const float* __restrict__ h2,    // [N][32]
                                              const int* __restrict__ gstart,
                                              float* __restrict__ psum)        // [G][48]
{
    __shared__ float part[4][48];
    int g = blockIdx.x;
    int wave = threadIdx.x >> 6;
    int lane = threadIdx.x & 63;
    int s = gstart[g], e = gstart[g + 1];
    if (lane < 48) {
        float a0 = 0.f, a1 = 0.f;
        if (lane < 16) {
            int n = s + wave;
            for (; n + 4 < e; n += 8) {
                a0 += agg[n * 16 + lane];
                a1 += agg[(n + 4) * 16 + lane];
            }
            if (n < e) a0 += agg[n * 16 + lane];
        } else {
            int d = lane - 16;
            int n = s + wave;
            for (; n + 4 < e; n += 8) {
                a0 += h2[n * 32 + d];
                a1 += h2[(n + 4) * 32 + d];
            }
            if (n < e) a0 += h2[n * 32 + d];
        }
        part[wave][lane] = a0 + a1;
    }
    __syncthreads();
    if (threadIdx.x < 48)
        psum[g * 48 + threadIdx.x] = part[0][threadIdx.x] + part[1][threadIdx.x]
                                   + part[2][threadIdx.x] + part[3][threadIdx.x];
}

// -------- finalize --------
__global__ __launch_bounds__(256) void k_finalize2(const float* __restrict__ psum,  // [G][48]
                                                   const float* __restrict__ Wroot, // [16][32]
                                                   const float* __restrict__ b,
                                                   const int* __restrict__ gstart,
                                                   float* __restrict__ out) {
    __shared__ float sW[16 * 32];
    __shared__ float sb[16];
    int tid = threadIdx.x;
    for (int i = tid; i < 16 * 32; i += 256) sW[i] = Wroot[i];
    if (tid < 16) sb[tid] = b[tid];
    __syncthreads();
    int idx = blockIdx.x * 256 + tid;   // (g, o)
    if (idx >= N_GRAPHS * 16) return;
    int g = idx >> 4;
    int o = idx & 15;
    float cnt = (float)(gstart[g + 1] - gstart[g]);
    const float* p = psum + g * 48;
    float acc = p[o] + cnt * sb[o];
#pragma unroll
    for (int k = 0; k < 32; ++k) acc += p[16 + k] * sW[o * 32 + k];
    out[idx] = fast_tanh(acc / fmaxf(cnt, 1.f));
}

extern "C" void kernel_launch(void* const* d_in, const int* in_sizes, int n_in,
                              void* d_out, int out_size, void* d_ws, size_t ws_size,
                              hipStream_t stream) {
    const float* x      = (const float*)d_in[0];
    const int*   eidx   = (const int*)d_in[1];
    const int*   src    = eidx;
    const int*   dst    = eidx + N_EDGES;
    const int*   batch  = (const int*)d_in[2];
    const float* Wrel0  = (const float*)d_in[3];
    const float* b0     = (const float*)d_in[4];
    const float* Wroot0 = (const float*)d_in[5];
    const float* Wrel1  = (const float*)d_in[6];
    const float* b1     = (const float*)d_in[7];
    const float* Wroot1 = (const float*)d_in[8];
    const float* Wrel2  = (const float*)d_in[9];
    const float* b2     = (const float*)d_in[10];
    const float* Wroot2 = (const float*)d_in[11];
    float* out = (float*)d_out;

    // ---- workspace layout ----
    float* ws   = (float*)d_ws;
    float* agg  = ws;                                  // N*40 f32 (stride 40; reused 40/32/16)
    float* r1   = agg + (size_t)N_NODES * 40;          // N*32 f32 (alias: xb [N][20] before fused0)
    float* h2   = r1  + (size_t)N_NODES * 32;          // N*32 f32
    unsigned int* ybuf = (unsigned int*)(h2 + (size_t)N_NODES * 32); // N*16 uints (y1b; y2b reuses)
    float* psum = (float*)(ybuf + (size_t)N_NODES * 16);             // 256*48
    int* rowptr      = (int*)(psum + N_GRAPHS * 48);   // N
    int* rowend      = rowptr + N_NODES;               // N
    int* gstart      = rowend + N_NODES;               // 257 (pad 260)
    int* bucket_cnt  = gstart + 260;                   // NB (pad 400)
    int* ebuf        = bucket_cnt + 400;               // NB*CAP (~14.5 MB), becomes node-sorted elist
    unsigned int* xb = (unsigned int*)r1;              // [N][20] (dead before fused0 writes r1)
    unsigned int* y1b = ybuf;                          // [N][16]
    unsigned int* y2b = ybuf;                          // [N][8] (y1b dead after L1 gather)

    // ---- cast x to padded bf16 pair table [N][20] ----
    k_cast_pad<<<(N_NODES * 20 + 255) / 256, 256, 0, stream>>>(x, xb);

    // ---- CSR build (fused scatter + LDS-staged per-bucket node sort) + graph boundaries ----
    hipMemsetAsync(bucket_cnt, 0, sizeof(int) * NB, stream);
    k_scatter2<<<NBLK, 256, 0, stream>>>(src, dst, bucket_cnt, ebuf);
    k_bucket_csr2<<<NB, 512, 0, stream>>>(bucket_cnt, ebuf, rowptr, rowend);
    k_graph_start<<<(N_NODES + 255) / 256, 256, 0, stream>>>(batch, gstart);

    // ---- Layer 0: quad gather (5 quads, 16B loads), then fused dense ----
    k_gather_quad<5, 20, 40><<<(N_NODES * 5 + 255) / 256, 256, 0, stream>>>(xb, rowptr, rowend, ebuf, agg);
    k_fused0<<<(N_NODES + 255) / 256, 256, 0, stream>>>(agg, x, Wrel0, b0, Wroot0,
                                                        Wrel1, b1, Wroot1, y1b, r1);

    // ---- Layer 1: quad gather (4 quads), then fused finish + layer2-rel ----
    k_gather_quad<4, 16, 32><<<(N_NODES * 4 + 255) / 256, 256, 0, stream>>>(y1b, rowptr, rowend, ebuf, agg);
    k_fused1<<<(N_NODES + 255) / 256, 256, 0, stream>>>(agg, r1, Wrel2, h2, y2b);

    // ---- Layer 2: quad gather (2 quads) ----
    k_gather_quad<2, 8, 16><<<(N_NODES * 2 + 255) / 256, 256, 0, stream>>>(y2b, rowptr, rowend, ebuf, agg);

    // ---- pool + finalize ----
    k_pool<<<N_GRAPHS, 256, 0, stream>>>(agg, h2, gstart, psum);
    k_finalize2<<<(N_GRAPHS * 16 + 255) / 256, 256, 0, stream>>>(psum, Wroot2, b2, gstart, out);
}